// Round 2
// baseline (243.718 us; speedup 1.0000x reference)
//
#include <hip/hip_runtime.h>

// Reference reduces to: out = box3x3_zeropad(x) + x + bias[c]
// because softmax over a size-1 axis is identically 1.0 (the w1/w2 matmul
// branch is algebraically dead). Pure memory-bound 3x3 stencil.
//
// x: (32, 256, 64, 64) fp32  -> 8192 planes of 64x64
// One block per plane, 256 threads, LDS-staged with zeroed halo.
// Traffic floor: 134 MB read + 134 MB write -> ~43 us at 6.3 TB/s.

#define PLANES 8192
#define H 64
#define W 64
#define SMH 66   // 64 rows + 1 halo row top/bottom
#define SMW 72   // interior cols at 4..67; halo col 3 (left), 68 (right); f4-aligned reads up to col 71

__global__ __launch_bounds__(256) void dynamic_dwconv_box_kernel(
    const float* __restrict__ x,
    const float* __restrict__ bias,
    float* __restrict__ out)
{
    __shared__ float sm[SMH * SMW];
    const int p   = blockIdx.x;      // plane index 0..8191
    const int c   = p & 255;         // channel (c = p % 256)
    const int tid = threadIdx.x;

    // Zero ONLY the halo cells the compute phase reads:
    //   row 0 (full), row 65 (full), col 3 rows 1..64, col 68 rows 1..64.
    // These are disjoint from the staged interior (rows 1..64, cols 4..67),
    // so zeroing and staging share one barrier.
    for (int i = tid; i < 2 * SMW + 2 * 64; i += 256) {
        int idx;
        if (i < SMW)                 idx = i;                                  // row 0
        else if (i < 2 * SMW)        idx = 65 * SMW + (i - SMW);               // row 65
        else if (i < 2 * SMW + 64)   idx = (i - 2 * SMW + 1) * SMW + 3;        // col 3
        else                         idx = (i - 2 * SMW - 64 + 1) * SMW + 68;  // col 68
        sm[idx] = 0.0f;
    }

    // Stage 64x64 interior: 1024 float4 loads, 4 per thread.
    // Each wave reads 4 KB contiguous -> perfect coalescing.
    const float* xp = x + (size_t)p * (H * W);
    #pragma unroll
    for (int ch = 0; ch < 4; ++ch) {
        int l  = ch * 256 + tid;     // 0..1023
        int r  = l >> 4;             // row 0..63
        int c4 = (l & 15) << 2;      // col 0,4,...,60
        float4 v = *reinterpret_cast<const float4*>(xp + r * W + c4);
        *reinterpret_cast<float4*>(&sm[(r + 1) * SMW + (c4 + 4)]) = v;
    }
    __syncthreads();

    // Each thread: 16 outputs of one row. r = interior row, cs = col base.
    const int r  = tid >> 2;         // 0..63
    const int cs = (tid & 3) << 4;   // 0,16,32,48
    const float bval = bias[c];

    float acc[16];
    float center[16];
    #pragma unroll
    for (int k = 0; k < 16; ++k) acc[k] = 0.0f;

    // 9-point box sum: 3 rows x horizontal triple-sums over an 18-value window
    // (interior cols cs-1 .. cs+16 == sm cols cs+3 .. cs+20).
    // All LDS reads are aligned ds_read_b128 (2-way bank aliasing == free);
    // the halo values come from the .w/.x lanes of aligned float4s.
    #pragma unroll
    for (int dr = 0; dr < 3; ++dr) {
        const float* row = &sm[(r + dr) * SMW + cs];
        float v[18];
        {
            float4 L = *reinterpret_cast<const float4*>(row);       // sm cols cs..cs+3
            v[0] = L.w;                                             // interior col cs-1
        }
        #pragma unroll
        for (int q = 0; q < 4; ++q) {
            float4 t = *reinterpret_cast<const float4*>(row + 4 + q * 4);
            v[1 + q * 4 + 0] = t.x;
            v[1 + q * 4 + 1] = t.y;
            v[1 + q * 4 + 2] = t.z;
            v[1 + q * 4 + 3] = t.w;
        }
        {
            float4 R = *reinterpret_cast<const float4*>(row + 20);  // sm cols cs+20..cs+23
            v[17] = R.x;                                            // interior col cs+16
        }
        #pragma unroll
        for (int k = 0; k < 16; ++k) acc[k] += v[k] + v[k + 1] + v[k + 2];
        if (dr == 1) {
            #pragma unroll
            for (int k = 0; k < 16; ++k) center[k] = v[k + 1];
        }
    }

    // out = box-sum + x + bias ; float4 stores (wave covers 4 KB contiguous
    // across its 4 store instructions; lines fully written -> merges in L2).
    float* op = out + (size_t)p * (H * W) + r * W + cs;
    #pragma unroll
    for (int q = 0; q < 4; ++q) {
        float4 o;
        o.x = acc[q * 4 + 0] + center[q * 4 + 0] + bval;
        o.y = acc[q * 4 + 1] + center[q * 4 + 1] + bval;
        o.z = acc[q * 4 + 2] + center[q * 4 + 2] + bval;
        o.w = acc[q * 4 + 3] + center[q * 4 + 3] + bval;
        *reinterpret_cast<float4*>(op + q * 4) = o;
    }
}

extern "C" void kernel_launch(void* const* d_in, const int* in_sizes, int n_in,
                              void* d_out, int out_size, void* d_ws, size_t ws_size,
                              hipStream_t stream)
{
    const float* x    = (const float*)d_in[0];
    // d_in[1..4] = w1, b1, w2, b2 : algebraically dead (softmax over size-1 axis == 1)
    const float* bias = (const float*)d_in[5];
    float* out        = (float*)d_out;

    dynamic_dwconv_box_kernel<<<PLANES, 256, 0, stream>>>(x, bias, out);
}